// Round 12
// baseline (387.291 us; speedup 1.0000x reference)
//
#include <hip/hip_runtime.h>
#include <hip/hip_bf16.h>
#include <math.h>

typedef __bf16 bf16_t;
typedef __attribute__((ext_vector_type(8))) __bf16 bx8;
typedef __attribute__((ext_vector_type(4))) __bf16 bx4;
typedef __attribute__((ext_vector_type(4))) short sx4;
typedef __attribute__((ext_vector_type(4))) float fx4;

#define DEV __device__ __forceinline__

// async global->LDS, 16B per lane. LDS dest must be wave-uniform base (HW adds lane*16).
DEV void async_copy16(void* lds, const void* g) {
    __builtin_amdgcn_global_load_lds(
        (const __attribute__((address_space(1))) unsigned int*)g,
        (__attribute__((address_space(3))) unsigned int*)lds, 16, 0, 0);
}

// 16x16x16 bf16 MFMA (legacy shape, carried to gfx950; builtin name varies by ROCm)
DEV fx4 mfma16(bx4 a, bx4 b, fx4 c) {
#if __has_builtin(__builtin_amdgcn_mfma_f32_16x16x16bf16_1k)
    return __builtin_amdgcn_mfma_f32_16x16x16bf16_1k(
        __builtin_bit_cast(sx4, a), __builtin_bit_cast(sx4, b), c, 0, 0, 0);
#elif __has_builtin(__builtin_amdgcn_mfma_f32_16x16x16_bf16)
    return __builtin_amdgcn_mfma_f32_16x16x16_bf16(a, b, c, 0, 0, 0);
#else
    asm("v_mfma_f32_16x16x16_bf16 %0, %1, %2, %0" : "+v"(c) : "v"(a), "v"(b));
    return c;
#endif
}

// ---------------------------------------------------------------- convert
__global__ void __launch_bounds__(256) cvt_bf16(const float* __restrict__ in,
                                                bf16_t* __restrict__ out, int n) {
    int i = (blockIdx.x * 256 + threadIdx.x) * 4;
    if (i + 3 < n) {
        float4 v = *(const float4*)(in + i);
        bx4 o = { (__bf16)v.x, (__bf16)v.y, (__bf16)v.z, (__bf16)v.w };
        *(bx4*)(out + i) = o;
    }
}

// ---------------------------------------------------------------- GEMM C = A[MxK] * B[NxK]^T
// r11 BK=64 m97 variant (proven r11): plane-major LDS [2 kplanes][128 rows][32], 32 iters.
// r12: QKV call scales Q columns (n0<2048) by CEXP in the epilogue (block-uniform) so
// attn's exp2 needs no per-element multiply.
template <bool BF16_OUT>
__global__ void __launch_bounds__(256, 2) gemm_bt(const bf16_t* __restrict__ A,
                                                  const bf16_t* __restrict__ B,
                                                  void* __restrict__ C,
                                                  int M, int N, int K, float scale0) {
    __shared__ bf16_t As[2 * 4096];   // 16 KB: kplane*4096 + row*32 + e
    __shared__ bf16_t Bs[2 * 4096];   // 16 KB
    const int tid = threadIdx.x;
    const int w = tid >> 6, lane = tid & 63;
    const int ln = lane & 15, quad = lane >> 4;
    const int m0 = blockIdx.y * 128, n0 = blockIdx.x * 128;
    const int wm = (w >> 1) * 64, wn = (w & 1) * 64;
    const float scale = (n0 < 2048) ? scale0 : 1.0f;

    fx4 acc[4][4];
#pragma unroll
    for (int i = 0; i < 4; ++i)
#pragma unroll
        for (int j = 0; j < 4; ++j) acc[i][j] = (fx4){0.f, 0.f, 0.f, 0.f};

    for (int k0 = 0; k0 < K; k0 += 64) {
#pragma unroll
        for (int call = 0; call < 4; ++call) {
            int c = w * 256 + call * 64 + lane;
            int p = c >> 9, row = (c >> 2) & 127, piece = c & 3;
            async_copy16(As + (size_t)(w * 256 + call * 64) * 8,
                         A + (size_t)(m0 + row) * K + k0 + p * 32 + piece * 8);
            async_copy16(Bs + (size_t)(w * 256 + call * 64) * 8,
                         B + (size_t)(n0 + row) * K + k0 + p * 32 + piece * 8);
        }
        __syncthreads();

#pragma unroll
        for (int kk = 0; kk < 2; ++kk) {
            bx8 af[4], bf[4];
#pragma unroll
            for (int i = 0; i < 4; ++i)
                af[i] = *(const bx8*)(As + (size_t)kk * 4096 + (wm + i * 16 + ln) * 32 + quad * 8);
#pragma unroll
            for (int j = 0; j < 4; ++j)
                bf[j] = *(const bx8*)(Bs + (size_t)kk * 4096 + (wn + j * 16 + ln) * 32 + quad * 8);
#pragma unroll
            for (int i = 0; i < 4; ++i)
#pragma unroll
                for (int j = 0; j < 4; ++j)
                    acc[i][j] = __builtin_amdgcn_mfma_f32_16x16x32_bf16(af[i], bf[j], acc[i][j], 0, 0, 0);
        }
        __syncthreads();
    }

#pragma unroll
    for (int i = 0; i < 4; ++i) {
        int mrow = m0 + wm + i * 16 + quad * 4;
#pragma unroll
        for (int j = 0; j < 4; ++j) {
            int ncol = n0 + wn + j * 16 + ln;
#pragma unroll
            for (int r = 0; r < 4; ++r) {
                if (BF16_OUT)
                    ((bf16_t*)C)[(size_t)(mrow + r) * N + ncol] = (__bf16)(acc[i][j][r] * scale);
                else
                    ((float*)C)[(size_t)(mrow + r) * N + ncol] = acc[i][j][r];
            }
        }
    }
}

// ---------------------------------------------------------------- V pack: [b,t,hd] -> VP[bh][key/4][hd][key%4]
// LDS-free register repack. One 16B out chunk per thread: (q4, hd pair c) <- 4 dwords of
// 4 consecutive key rows. Reads coalesced (lane=c -> consecutive dwords), writes coalesced.
__global__ void __launch_bounds__(256) vpack(const bf16_t* __restrict__ qkv,
                                             bf16_t* __restrict__ vp) {
    int g = blockIdx.x * 256 + threadIdx.x;   // 0..1048575
    int bh = g >> 15;
    int rem = g & 32767;
    int q4 = rem >> 6;                         // 0..511
    int c  = rem & 63;                         // hd-pair id
    int b = bh >> 4, h = bh & 15;
    const bf16_t* src = qkv + (size_t)(b * 2048 + q4 * 4) * 6144 + 4096 + h * 128 + c * 2;
    unsigned u0 = *(const unsigned*)(src);
    unsigned u1 = *(const unsigned*)(src + 6144);
    unsigned u2 = *(const unsigned*)(src + 12288);
    unsigned u3 = *(const unsigned*)(src + 18432);
    uint4 outv;
    outv.x = (u0 & 0xffffu) | (u1 << 16);          // (hd=2c,  k3=0,1)
    outv.y = (u2 & 0xffffu) | (u3 << 16);          // (hd=2c,  k3=2,3)
    outv.z = (u0 >> 16) | (u1 & 0xffff0000u);      // (hd=2c+1,k3=0,1)
    outv.w = (u2 >> 16) | (u3 & 0xffff0000u);      // (hd=2c+1,k3=2,3)
    *(uint4*)(vp + (size_t)g * 8) = outv;
}

// ---------------------------------------------------------------- flash attention
// grid: 512 blocks (XCD-remapped), block 256 = 4 waves. wave w: q rows [w*32, w*32+32).
// r12: REGISTER-ONLY P (T12 via K=16 MFMA):
//   - swapped QK^T: s_t = mfma32(kf, qf) -> lane holds S^T[key=quad*4+r][q=ln]
//   - that IS the A-frag layout of mfma 16x16x16 (m=ln, k=quad*4+e): exp2 -> pack bx4 ->
//     PV with K=16 MFMAs. No P LDS write/read, no swizzle, Ps buffer gone.
//   - V staged from VP[bh][key/4][hd][key%4]: B-frag (n=ln=hd-col, k=quad*4+e=key) is one
//     conflict-free ds_read_b64 (16 slots x 4-way = min phases). Staging linear+coalesced.
//   - CEXP pre-folded into Q by the QKV GEMM -> exp2f(s) direct.
// Carried: Ks plane-major (conflict-free), no-max softmax, lsum via ones-MFMA, XCD remap.
// LDS 64 KB -> 2 blocks/CU.
__global__ void __launch_bounds__(256, 2) attn(const bf16_t* __restrict__ qkv,
                                               const bf16_t* __restrict__ vp,
                                               bf16_t* __restrict__ y) {
    __shared__ bf16_t Ks[128 * 128];   // 32 KB: [4 pl(hd)][128 key][32 hd]
    __shared__ bf16_t Vs[16384];       // 32 KB: [32 q4][128 hd][4 k3]
    const int tid = threadIdx.x;
    const int w = tid >> 6, lane = tid & 63;
    const int ln = lane & 15, quad = lane >> 4;
    const int lin = blockIdx.x;
    const int slot = lin >> 3;
    const int bh = (lin & 7) + ((slot >> 4) << 3);
    const int qt = slot & 15;
    const int b = bh >> 4, h = bh & 15;

    const bf16_t* Qb = qkv + (size_t)(b * 2048 + qt * 128) * 6144 + h * 128;
    const bf16_t* Kb = qkv + (size_t)(b * 2048) * 6144 + 2048 + h * 128;
    const bf16_t* VPb = vp + (size_t)bh * 262144;

    // Q B-fragments (B[n=q=ln][k=hd=quad*8+e]) — same load pattern as before, Q pre-scaled
    bx8 qf[2][4];
#pragma unroll
    for (int i = 0; i < 2; ++i)
#pragma unroll
        for (int kk = 0; kk < 4; ++kk)
            qf[i][kk] = *(const bx8*)(Qb + (size_t)(w * 32 + i * 16 + ln) * 6144 + kk * 32 + quad * 8);

    const __bf16 one = (__bf16)1.0f;
    const bx4 ones4 = { one, one, one, one };

    fx4 o[2][8];
#pragma unroll
    for (int i = 0; i < 2; ++i)
#pragma unroll
        for (int j = 0; j < 8; ++j) o[i][j] = (fx4){0.f, 0.f, 0.f, 0.f};
    fx4 lsum[2];
#pragma unroll
    for (int i = 0; i < 2; ++i) lsum[i] = (fx4){0.f, 0.f, 0.f, 0.f};

    for (int kt = 0; kt < 16; ++kt) {
        // stage K plane-major (as r9) + VP linear (perfectly coalesced source)
#pragma unroll
        for (int call = 0; call < 8; ++call) {
            int cp = call * 64 + lane;
            int row = cp >> 2, piece = cp & 3;
            async_copy16(Ks + (size_t)w * 4096 + call * 512,
                         Kb + (size_t)(kt * 128 + row) * 6144 + w * 32 + piece * 8);
            async_copy16(Vs + (size_t)w * 4096 + call * 512,
                         VPb + (size_t)kt * 16384 + (w * 8 + call) * 512 + lane * 8);
        }
        __syncthreads();

        // 4 quarters over keys (32 each = key-tiles 2q, 2q+1)
#pragma unroll
        for (int q = 0; q < 4; ++q) {
            // swapped QK^T: S^T tiles [key16][q16]
            fx4 st[2][2];
#pragma unroll
            for (int i = 0; i < 2; ++i)
#pragma unroll
                for (int jj = 0; jj < 2; ++jj) st[i][jj] = (fx4){0.f, 0.f, 0.f, 0.f};
#pragma unroll
            for (int kk = 0; kk < 4; ++kk) {
                bx8 kf0 = *(const bx8*)(Ks + (size_t)kk * 4096 + ((2 * q) * 16 + ln) * 32 + quad * 8);
                bx8 kf1 = *(const bx8*)(Ks + (size_t)kk * 4096 + ((2 * q + 1) * 16 + ln) * 32 + quad * 8);
#pragma unroll
                for (int i = 0; i < 2; ++i) {
                    st[i][0] = __builtin_amdgcn_mfma_f32_16x16x32_bf16(kf0, qf[i][kk], st[i][0], 0, 0, 0);
                    st[i][1] = __builtin_amdgcn_mfma_f32_16x16x32_bf16(kf1, qf[i][kk], st[i][1], 0, 0, 0);
                }
            }

            // exp2 in-register (Q pre-scaled) -> P A-fragments for K=16 MFMA
            bx4 pa[2][2];
#pragma unroll
            for (int i = 0; i < 2; ++i)
#pragma unroll
                for (int jj = 0; jj < 2; ++jj) {
                    bx4 t = { (__bf16)exp2f(st[i][jj][0]), (__bf16)exp2f(st[i][jj][1]),
                              (__bf16)exp2f(st[i][jj][2]), (__bf16)exp2f(st[i][jj][3]) };
                    pa[i][jj] = t;
                }

            // PV (K=16): o[q-rows][d] += P * V over this quarter's 32 keys
#pragma unroll
            for (int jj = 0; jj < 2; ++jj) {
                const int kt8 = 2 * q + jj;
                bx4 vf[8];
#pragma unroll
                for (int j = 0; j < 8; ++j)
                    vf[j] = *(const bx4*)(Vs + (size_t)(kt8 * 4 + quad) * 512 + (j * 16 + ln) * 4);
#pragma unroll
                for (int i = 0; i < 2; ++i) {
#pragma unroll
                    for (int j = 0; j < 8; ++j)
                        o[i][j] = mfma16(pa[i][jj], vf[j], o[i][j]);
                    lsum[i] = mfma16(pa[i][jj], ones4, lsum[i]);
                }
            }
        }
        __syncthreads();
    }

    // epilogue: y[b,t,h*128+hd] bf16 (o rows q=quad*4+r, cols d=ln — unchanged layout)
#pragma unroll
    for (int i = 0; i < 2; ++i)
#pragma unroll
        for (int r = 0; r < 4; ++r) {
            float rl = 1.0f / lsum[i][r];
#pragma unroll
            for (int j = 0; j < 8; ++j) {
                int t = qt * 128 + w * 32 + i * 16 + quad * 4 + r;
                int col = h * 128 + j * 16 + ln;
                y[(size_t)(b * 2048 + t) * 2048 + col] = (__bf16)(o[i][j][r] * rl);
            }
        }
}

// ---------------------------------------------------------------- launch
extern "C" void kernel_launch(void* const* d_in, const int* in_sizes, int n_in,
                              void* d_out, int out_size, void* d_ws, size_t ws_size,
                              hipStream_t stream) {
    const float* x    = (const float*)d_in[0];
    const float* wqkv = (const float*)d_in[1];
    const float* wo   = (const float*)d_in[2];
    float* out = (float*)d_out;
    char* ws = (char*)d_ws;
    const float CEXP = 0.08838834764831845f * 1.44269504088896340f;  // (1/sqrt(128))*log2(e)

    // workspace layout (112 MB total)
    bf16_t* Xb  = (bf16_t*)(ws);                          // 16 MB  (reused as Y after QKV GEMM)
    bf16_t* Wqb = (bf16_t*)(ws + (size_t)(16u << 20));    // 24 MB
    bf16_t* Wob = (bf16_t*)(ws + (size_t)(40u << 20));    //  8 MB
    bf16_t* QKV = (bf16_t*)(ws + (size_t)(48u << 20));    // 48 MB
    bf16_t* VP  = (bf16_t*)(ws + (size_t)(96u << 20));    // 16 MB
    bf16_t* Y   = Xb;

    cvt_bf16<<<8388608 / 1024, 256, 0, stream>>>(x, Xb, 8388608);
    cvt_bf16<<<12582912 / 1024, 256, 0, stream>>>(wqkv, Wqb, 12582912);
    cvt_bf16<<<4194304 / 1024, 256, 0, stream>>>(wo, Wob, 4194304);

    // QKV = X * Wqkv^T  [4096 x 6144]; Q columns pre-scaled by CEXP
    gemm_bt<true><<<dim3(48, 32), 256, 0, stream>>>(Xb, Wqb, QKV, 4096, 6144, 2048, CEXP);
    // V -> VP[bh][key/4][hd][key%4]
    vpack<<<4096, 256, 0, stream>>>(QKV, VP);
    // flash attention -> Y [4096 x 2048] bf16  (1-D grid, XCD-remapped inside)
    attn<<<dim3(512), 256, 0, stream>>>(QKV, VP, Y);
    // out = Y * Wo^T  [4096 x 2048] fp32
    gemm_bt<false><<<dim3(16, 32), 256, 0, stream>>>(Y, Wob, out, 4096, 2048, 2048, 1.0f);
}

// Round 13
// 368.331 us; speedup vs baseline: 1.0515x; 1.0515x over previous
//
#include <hip/hip_runtime.h>
#include <hip/hip_bf16.h>
#include <math.h>

typedef __bf16 bf16_t;
typedef __attribute__((ext_vector_type(8))) __bf16 bx8;
typedef __attribute__((ext_vector_type(4))) __bf16 bx4;
typedef __attribute__((ext_vector_type(4))) short sx4;
typedef __attribute__((ext_vector_type(4))) float fx4;

#define DEV __device__ __forceinline__

// async global->LDS, 16B per lane. LDS dest must be wave-uniform base (HW adds lane*16).
DEV void async_copy16(void* lds, const void* g) {
    __builtin_amdgcn_global_load_lds(
        (const __attribute__((address_space(1))) unsigned int*)g,
        (__attribute__((address_space(3))) unsigned int*)lds, 16, 0, 0);
}

// 16x16x16 bf16 MFMA (legacy shape, carried to gfx950; builtin name varies by ROCm)
DEV fx4 mfma16(bx4 a, bx4 b, fx4 c) {
#if __has_builtin(__builtin_amdgcn_mfma_f32_16x16x16bf16_1k)
    return __builtin_amdgcn_mfma_f32_16x16x16bf16_1k(
        __builtin_bit_cast(sx4, a), __builtin_bit_cast(sx4, b), c, 0, 0, 0);
#elif __has_builtin(__builtin_amdgcn_mfma_f32_16x16x16_bf16)
    return __builtin_amdgcn_mfma_f32_16x16x16_bf16(a, b, c, 0, 0, 0);
#else
    asm("v_mfma_f32_16x16x16_bf16 %0, %1, %2, %0" : "+v"(c) : "v"(a), "v"(b));
    return c;
#endif
}

// ---------------------------------------------------------------- fused convert (r13: 1 launch)
// segments: x 8388608 | wqkv 12582912 | wo 4194304 — all multiples of 1024, no straddle.
__global__ void __launch_bounds__(256) cvt_all(const float* __restrict__ x,
                                               const float* __restrict__ wq,
                                               const float* __restrict__ wo,
                                               bf16_t* __restrict__ xb,
                                               bf16_t* __restrict__ wqb,
                                               bf16_t* __restrict__ wob) {
    int i = (blockIdx.x * 256 + threadIdx.x) * 4;
    const float* in;
    bf16_t* out;
    int k;
    if (i < 8388608) { in = x; out = xb; k = i; }
    else if (i < 8388608 + 12582912) { in = wq; out = wqb; k = i - 8388608; }
    else { in = wo; out = wob; k = i - (8388608 + 12582912); }
    float4 v = *(const float4*)(in + k);
    bx4 o = { (__bf16)v.x, (__bf16)v.y, (__bf16)v.z, (__bf16)v.w };
    *(bx4*)(out + k) = o;
}

// ---------------------------------------------------------------- GEMM C = A[MxK] * B[NxK]^T
// r11 BK=64 m97 variant: plane-major LDS [2 kplanes][128 rows][32], 32 K-iters, 2 blk/CU.
// r12: Q columns (n0<2048) scaled by CEXP in epilogue.
// r13: V columns (n0>=4096, when VP != null) written DIRECTLY in packed layout
//   vp[bh][key>>2][hd][key&3] — acc rows r map to key&3 contiguously -> one bx4 store per
//   fragment. Replaces the vpack kernel (64 MB traffic + launch) with zero extra cost.
template <bool BF16_OUT>
__global__ void __launch_bounds__(256, 2) gemm_bt(const bf16_t* __restrict__ A,
                                                  const bf16_t* __restrict__ B,
                                                  void* __restrict__ C,
                                                  bf16_t* __restrict__ VP,
                                                  int M, int N, int K, float scale0) {
    __shared__ bf16_t As[2 * 4096];   // 16 KB: kplane*4096 + row*32 + e
    __shared__ bf16_t Bs[2 * 4096];   // 16 KB
    const int tid = threadIdx.x;
    const int w = tid >> 6, lane = tid & 63;
    const int ln = lane & 15, quad = lane >> 4;
    const int m0 = blockIdx.y * 128, n0 = blockIdx.x * 128;
    const int wm = (w >> 1) * 64, wn = (w & 1) * 64;
    const float scale = (n0 < 2048) ? scale0 : 1.0f;

    fx4 acc[4][4];
#pragma unroll
    for (int i = 0; i < 4; ++i)
#pragma unroll
        for (int j = 0; j < 4; ++j) acc[i][j] = (fx4){0.f, 0.f, 0.f, 0.f};

    for (int k0 = 0; k0 < K; k0 += 64) {
#pragma unroll
        for (int call = 0; call < 4; ++call) {
            int c = w * 256 + call * 64 + lane;
            int p = c >> 9, row = (c >> 2) & 127, piece = c & 3;
            async_copy16(As + (size_t)(w * 256 + call * 64) * 8,
                         A + (size_t)(m0 + row) * K + k0 + p * 32 + piece * 8);
            async_copy16(Bs + (size_t)(w * 256 + call * 64) * 8,
                         B + (size_t)(n0 + row) * K + k0 + p * 32 + piece * 8);
        }
        __syncthreads();

#pragma unroll
        for (int kk = 0; kk < 2; ++kk) {
            bx8 af[4], bf[4];
#pragma unroll
            for (int i = 0; i < 4; ++i)
                af[i] = *(const bx8*)(As + (size_t)kk * 4096 + (wm + i * 16 + ln) * 32 + quad * 8);
#pragma unroll
            for (int j = 0; j < 4; ++j)
                bf[j] = *(const bx8*)(Bs + (size_t)kk * 4096 + (wn + j * 16 + ln) * 32 + quad * 8);
#pragma unroll
            for (int i = 0; i < 4; ++i)
#pragma unroll
                for (int j = 0; j < 4; ++j)
                    acc[i][j] = __builtin_amdgcn_mfma_f32_16x16x32_bf16(af[i], bf[j], acc[i][j], 0, 0, 0);
        }
        __syncthreads();
    }

    if (VP != nullptr && n0 >= 4096) {
        // V block: write packed VP[bh][key>>2][hd][key&3]; bh/h/b block-uniform.
        const int h = (n0 - 4096) >> 7;
        const int bidx = m0 >> 11;
        bf16_t* vpb = VP + (size_t)(bidx * 16 + h) * 262144;
        const int key_base = (m0 & 2047) + wm;
#pragma unroll
        for (int i = 0; i < 4; ++i) {
            int key = key_base + i * 16 + quad * 4;   // multiple of 4; acc r -> key&3
#pragma unroll
            for (int j = 0; j < 4; ++j) {
                int hd = wn + j * 16 + ln;
                bx4 v = { (__bf16)acc[i][j][0], (__bf16)acc[i][j][1],
                          (__bf16)acc[i][j][2], (__bf16)acc[i][j][3] };
                *(bx4*)(vpb + (size_t)(key >> 2) * 512 + hd * 4) = v;
            }
        }
    } else {
#pragma unroll
        for (int i = 0; i < 4; ++i) {
            int mrow = m0 + wm + i * 16 + quad * 4;
#pragma unroll
            for (int j = 0; j < 4; ++j) {
                int ncol = n0 + wn + j * 16 + ln;
#pragma unroll
                for (int r = 0; r < 4; ++r) {
                    if (BF16_OUT)
                        ((bf16_t*)C)[(size_t)(mrow + r) * N + ncol] = (__bf16)(acc[i][j][r] * scale);
                    else
                        ((float*)C)[(size_t)(mrow + r) * N + ncol] = acc[i][j][r];
                }
            }
        }
    }
}

// ---------------------------------------------------------------- flash attention (r12 form)
// grid: 512 blocks (XCD-remapped), block 256 = 4 waves. wave w: q rows [w*32, w*32+32).
// Register-only P (swapped QK^T -> S^T lane-local -> exp2 -> bx4 A-frags -> K=16 PV MFMAs).
// V from VP[bh][key/4][hd][key%4] (conflict-free ds_read_b64, linear staging).
// CEXP pre-folded into Q. Ks plane-major, no-max softmax, lsum via ones-MFMA, XCD remap.
// LDS 64 KB -> 2 blocks/CU. Measured r12: MfmaUtil 44.8 + VALUBusy 43.6 (dual-pipe sat).
__global__ void __launch_bounds__(256, 2) attn(const bf16_t* __restrict__ qkv,
                                               const bf16_t* __restrict__ vp,
                                               bf16_t* __restrict__ y) {
    __shared__ bf16_t Ks[128 * 128];   // 32 KB: [4 pl(hd)][128 key][32 hd]
    __shared__ bf16_t Vs[16384];       // 32 KB: [32 q4][128 hd][4 k3]
    const int tid = threadIdx.x;
    const int w = tid >> 6, lane = tid & 63;
    const int ln = lane & 15, quad = lane >> 4;
    const int lin = blockIdx.x;
    const int slot = lin >> 3;
    const int bh = (lin & 7) + ((slot >> 4) << 3);
    const int qt = slot & 15;
    const int b = bh >> 4, h = bh & 15;

    const bf16_t* Qb = qkv + (size_t)(b * 2048 + qt * 128) * 6144 + h * 128;
    const bf16_t* Kb = qkv + (size_t)(b * 2048) * 6144 + 2048 + h * 128;
    const bf16_t* VPb = vp + (size_t)bh * 262144;

    bx8 qf[2][4];
#pragma unroll
    for (int i = 0; i < 2; ++i)
#pragma unroll
        for (int kk = 0; kk < 4; ++kk)
            qf[i][kk] = *(const bx8*)(Qb + (size_t)(w * 32 + i * 16 + ln) * 6144 + kk * 32 + quad * 8);

    const __bf16 one = (__bf16)1.0f;
    const bx4 ones4 = { one, one, one, one };

    fx4 o[2][8];
#pragma unroll
    for (int i = 0; i < 2; ++i)
#pragma unroll
        for (int j = 0; j < 8; ++j) o[i][j] = (fx4){0.f, 0.f, 0.f, 0.f};
    fx4 lsum[2];
#pragma unroll
    for (int i = 0; i < 2; ++i) lsum[i] = (fx4){0.f, 0.f, 0.f, 0.f};

    for (int kt = 0; kt < 16; ++kt) {
#pragma unroll
        for (int call = 0; call < 8; ++call) {
            int cp = call * 64 + lane;
            int row = cp >> 2, piece = cp & 3;
            async_copy16(Ks + (size_t)w * 4096 + call * 512,
                         Kb + (size_t)(kt * 128 + row) * 6144 + w * 32 + piece * 8);
            async_copy16(Vs + (size_t)w * 4096 + call * 512,
                         VPb + (size_t)kt * 16384 + (w * 8 + call) * 512 + lane * 8);
        }
        __syncthreads();

#pragma unroll
        for (int q = 0; q < 4; ++q) {
            fx4 st[2][2];
#pragma unroll
            for (int i = 0; i < 2; ++i)
#pragma unroll
                for (int jj = 0; jj < 2; ++jj) st[i][jj] = (fx4){0.f, 0.f, 0.f, 0.f};
#pragma unroll
            for (int kk = 0; kk < 4; ++kk) {
                bx8 kf0 = *(const bx8*)(Ks + (size_t)kk * 4096 + ((2 * q) * 16 + ln) * 32 + quad * 8);
                bx8 kf1 = *(const bx8*)(Ks + (size_t)kk * 4096 + ((2 * q + 1) * 16 + ln) * 32 + quad * 8);
#pragma unroll
                for (int i = 0; i < 2; ++i) {
                    st[i][0] = __builtin_amdgcn_mfma_f32_16x16x32_bf16(kf0, qf[i][kk], st[i][0], 0, 0, 0);
                    st[i][1] = __builtin_amdgcn_mfma_f32_16x16x32_bf16(kf1, qf[i][kk], st[i][1], 0, 0, 0);
                }
            }

            bx4 pa[2][2];
#pragma unroll
            for (int i = 0; i < 2; ++i)
#pragma unroll
                for (int jj = 0; jj < 2; ++jj) {
                    bx4 t = { (__bf16)exp2f(st[i][jj][0]), (__bf16)exp2f(st[i][jj][1]),
                              (__bf16)exp2f(st[i][jj][2]), (__bf16)exp2f(st[i][jj][3]) };
                    pa[i][jj] = t;
                }

#pragma unroll
            for (int jj = 0; jj < 2; ++jj) {
                const int kt8 = 2 * q + jj;
                bx4 vf[8];
#pragma unroll
                for (int j = 0; j < 8; ++j)
                    vf[j] = *(const bx4*)(Vs + (size_t)(kt8 * 4 + quad) * 512 + (j * 16 + ln) * 4);
#pragma unroll
                for (int i = 0; i < 2; ++i) {
#pragma unroll
                    for (int j = 0; j < 8; ++j)
                        o[i][j] = mfma16(pa[i][jj], vf[j], o[i][j]);
                    lsum[i] = mfma16(pa[i][jj], ones4, lsum[i]);
                }
            }
        }
        __syncthreads();
    }

#pragma unroll
    for (int i = 0; i < 2; ++i)
#pragma unroll
        for (int r = 0; r < 4; ++r) {
            float rl = 1.0f / lsum[i][r];
#pragma unroll
            for (int j = 0; j < 8; ++j) {
                int t = qt * 128 + w * 32 + i * 16 + quad * 4 + r;
                int col = h * 128 + j * 16 + ln;
                y[(size_t)(b * 2048 + t) * 2048 + col] = (__bf16)(o[i][j][r] * rl);
            }
        }
}

// ---------------------------------------------------------------- launch
extern "C" void kernel_launch(void* const* d_in, const int* in_sizes, int n_in,
                              void* d_out, int out_size, void* d_ws, size_t ws_size,
                              hipStream_t stream) {
    const float* x    = (const float*)d_in[0];
    const float* wqkv = (const float*)d_in[1];
    const float* wo   = (const float*)d_in[2];
    float* out = (float*)d_out;
    char* ws = (char*)d_ws;
    const float CEXP = 0.08838834764831845f * 1.44269504088896340f;  // (1/sqrt(128))*log2(e)

    // workspace layout (112 MB total)
    bf16_t* Xb  = (bf16_t*)(ws);                          // 16 MB  (reused as Y after QKV GEMM)
    bf16_t* Wqb = (bf16_t*)(ws + (size_t)(16u << 20));    // 24 MB
    bf16_t* Wob = (bf16_t*)(ws + (size_t)(40u << 20));    //  8 MB
    bf16_t* QKV = (bf16_t*)(ws + (size_t)(48u << 20));    // 48 MB (V region unused)
    bf16_t* VP  = (bf16_t*)(ws + (size_t)(96u << 20));    // 16 MB
    bf16_t* Y   = Xb;

    // one fused convert launch (25165824 elems, 4/thread)
    cvt_all<<<24576, 256, 0, stream>>>(x, wqkv, wo, Xb, Wqb, Wob);

    // QKV = X * Wqkv^T [4096 x 6144]; Q cols pre-scaled by CEXP; V cols -> VP packed
    gemm_bt<true><<<dim3(48, 32), 256, 0, stream>>>(Xb, Wqb, QKV, VP, 4096, 6144, 2048, CEXP);
    // flash attention -> Y [4096 x 2048] bf16  (1-D grid, XCD-remapped inside)
    attn<<<dim3(512), 256, 0, stream>>>(QKV, VP, Y);
    // out = Y * Wo^T  [4096 x 2048] fp32
    gemm_bt<false><<<dim3(16, 32), 256, 0, stream>>>(Y, Wob, out, nullptr, 4096, 2048, 2048, 1.0f);
}